// Round 6
// baseline (2830.610 us; speedup 1.0000x reference)
//
#include <hip/hip_runtime.h>
#include <math.h>

#define SEQLEN 1024
#define DIM 512
#define MM 512

typedef float f32x4 __attribute__((ext_vector_type(4)));
typedef float f32x2 __attribute__((ext_vector_type(2)));

__device__ __forceinline__ float sigf(float x) {
  return __builtin_amdgcn_rcpf(1.0f + __expf(-x));
}
__device__ __forceinline__ float tanhfast(float x) {
  return 1.0f - 2.0f * __builtin_amdgcn_rcpf(1.0f + __expf(2.0f * x));
}

// ---------------- K1: Gx[seq][t][g] = emb[ids[t]] . Wxcat[g] + bias_cat[g] ----------------
// Wxcat rows: [Wioux (1536 rows); Wfx (512 rows)], 512 cols.  Gx: [2][1024][2048]
__global__ __launch_bounds__(256) void gx_gemm(
    const int* __restrict__ l_ids, const int* __restrict__ r_ids,
    const float* __restrict__ emb,
    const float* __restrict__ Wioux, const float* __restrict__ Wfx,
    const float* __restrict__ bioux, const float* __restrict__ biouh,
    const float* __restrict__ bfx, const float* __restrict__ bfh,
    float* __restrict__ gx)
{
  __shared__ __align__(16) float At[32][68];   // transposed tiles: [k][row]
  __shared__ __align__(16) float Bt[32][68];
  const int tid = threadIdx.x;
  const int bid = blockIdx.x;
  const int seq = bid >> 9;            // 2
  const int tt  = (bid >> 5) & 15;     // 16 t-tiles of 64
  const int gt  = bid & 31;            // 32 g-tiles of 64
  const int t0 = tt * 64, g0 = gt * 64;
  const int* ids = seq ? r_ids : l_ids;

  const int li = tid >> 2;             // 0..63 (tile row)
  const int lk = (tid & 3) * 8;        // k chunk
  const float* arow = emb + (size_t)ids[t0 + li] * DIM;
  const int gg = g0 + li;
  const float* brow = (gg < 1536) ? (Wioux + (size_t)gg * DIM)
                                  : (Wfx + (size_t)(gg - 1536) * DIM);
  const int tr = tid >> 4;             // 0..15 micro-row group
  const int tc = tid & 15;             // 0..15 micro-col group

  float acc[4][4];
  #pragma unroll
  for (int i = 0; i < 4; ++i) { acc[i][0]=0.f; acc[i][1]=0.f; acc[i][2]=0.f; acc[i][3]=0.f; }

  for (int kb = 0; kb < 16; ++kb) {
    const int k0 = kb * 32;
    float4 av0 = *(const float4*)(arow + k0 + lk);
    float4 av1 = *(const float4*)(arow + k0 + lk + 4);
    float4 bv0 = *(const float4*)(brow + k0 + lk);
    float4 bv1 = *(const float4*)(brow + k0 + lk + 4);
    __syncthreads();
    At[lk+0][li]=av0.x; At[lk+1][li]=av0.y; At[lk+2][li]=av0.z; At[lk+3][li]=av0.w;
    At[lk+4][li]=av1.x; At[lk+5][li]=av1.y; At[lk+6][li]=av1.z; At[lk+7][li]=av1.w;
    Bt[lk+0][li]=bv0.x; Bt[lk+1][li]=bv0.y; Bt[lk+2][li]=bv0.z; Bt[lk+3][li]=bv0.w;
    Bt[lk+4][li]=bv1.x; Bt[lk+5][li]=bv1.y; Bt[lk+6][li]=bv1.z; Bt[lk+7][li]=bv1.w;
    __syncthreads();
    #pragma unroll
    for (int k = 0; k < 32; ++k) {
      float4 a4 = *(const float4*)&At[k][tr*4];
      float4 b4 = *(const float4*)&Bt[k][tc*4];
      acc[0][0]+=a4.x*b4.x; acc[0][1]+=a4.x*b4.y; acc[0][2]+=a4.x*b4.z; acc[0][3]+=a4.x*b4.w;
      acc[1][0]+=a4.y*b4.x; acc[1][1]+=a4.y*b4.y; acc[1][2]+=a4.y*b4.z; acc[1][3]+=a4.y*b4.w;
      acc[2][0]+=a4.z*b4.x; acc[2][1]+=a4.z*b4.y; acc[2][2]+=a4.z*b4.z; acc[2][3]+=a4.z*b4.w;
      acc[3][0]+=a4.w*b4.x; acc[3][1]+=a4.w*b4.y; acc[3][2]+=a4.w*b4.z; acc[3][3]+=a4.w*b4.w;
    }
  }
  const int gc = g0 + tc * 4;
  float badd[4];
  #pragma unroll
  for (int jj = 0; jj < 4; ++jj) {
    int g = gc + jj;
    badd[jj] = (g < 1536) ? (bioux[g] + biouh[g]) : (bfx[g-1536] + bfh[g-1536]);
  }
  #pragma unroll
  for (int ii = 0; ii < 4; ++ii) {
    float4 r;
    r.x = acc[ii][0] + badd[0];
    r.y = acc[ii][1] + badd[1];
    r.z = acc[ii][2] + badd[2];
    r.w = acc[ii][3] + badd[3];
    size_t off = ((size_t)seq * SEQLEN + (size_t)(t0 + tr*4 + ii)) * 2048 + gc;
    *(float4*)(gx + off) = r;
  }
}

// ---------------- K2: persistent scan, 256 WGs (seq-split), wave-per-j --------------------
// hbuf: [2 seq][2 parity][512 j][2] = {h, tag}; 8B atomic coherent publishes.
// WGs 0..127 -> seq L, 128..255 -> seq R. Wave wv of WG owns j = (wg&127)*4 + wv.
// Lane (gr = lane>>4 gate 0..3, c = lane&15 chunk): weights = row gr of j, cols c*32..+31,
// held in 8 NAMED f32x4 regs (no arrays -> nothing can be demoted to scratch; R3/4/5 disease).
// Per step: poll 1 dwordx4 (2 entries), stage 8B to padded LDS, 1 barrier, 8 broadcast
// ds_read_b128, 32 vec-FMA, 4 xor-reduce + gx + 3 xor gate-gather, lane0 cell + publish.
__global__ __launch_bounds__(256, 1) void lstm_scan(
    const float* __restrict__ Wiouh, const float* __restrict__ Wfh,
    const float* __restrict__ gx,
    float* __restrict__ hbuf,       // zeroed by memset (tags start at 0)
    float* __restrict__ hB)         // [2 seq][512]
{
  const int tid  = threadIdx.x;
  const int wgid = blockIdx.x;      // 0..255
  const int sq   = wgid >> 7;       // 0 = L, 1 = R
  const int wgs  = wgid & 127;
  const int wv   = tid >> 6;        // wave 0..3
  const int lane = tid & 63;
  const int gr   = lane >> 4;       // gate 0..3 (i,o,u,f)
  const int c    = lane & 15;       // col chunk (32 cols each)
  const int j    = wgs * 4 + wv;    // this wave's h index
  const bool owner = (lane == 0);

  float* hbase = hbuf + sq * 2048;              // [2 parity][512][2]
  const float* gxs = gx + (size_t)sq * SEQLEN * 2048;

  // weights: 8 named f32x4 (32 floats), loaded once — trivially register-resident
  const float* wrow = (gr < 3) ? (Wiouh + ((size_t)(gr * 512 + j)) * MM + c * 32)
                               : (Wfh + (size_t)j * MM + c * 32);
  f32x4 w0 = *(const f32x4*)(wrow + 0);
  f32x4 w1 = *(const f32x4*)(wrow + 4);
  f32x4 w2 = *(const f32x4*)(wrow + 8);
  f32x4 w3 = *(const f32x4*)(wrow + 12);
  f32x4 w4 = *(const f32x4*)(wrow + 16);
  f32x4 w5 = *(const f32x4*)(wrow + 20);
  f32x4 w6 = *(const f32x4*)(wrow + 24);
  f32x4 w7 = *(const f32x4*)(wrow + 28);
  asm volatile("" : "+v"(w0), "+v"(w1), "+v"(w2), "+v"(w3),
                    "+v"(w4), "+v"(w5), "+v"(w6), "+v"(w7));

  // h staging: 16 chunks x (32 data + 4 pad) floats; chunk c at hs[c*36..c*36+32)
  __shared__ __align__(16) float hs[16 * 36];

  float cst = 0.0f;                 // persistent c for owner lanes

  for (int t = 0; t < SEQLEN; ++t) {
    // gx pre-act for this lane's gate (c==0 lanes only); issued before the poll
    float gxv = 0.0f;
    if (c == 0) gxv = gxs[(size_t)t * 2048 + gr * 512 + j];

    // ---- poll own 2 entries (one dwordx4), tight spin ----
    const float* pp = hbase + (size_t)((t & 1) * 1024 + tid * 4);
    const float tf = (float)t;
    f32x4 e;
    for (;;) {
      asm volatile("global_load_dwordx4 %0, %1, off sc0 sc1\n\t"
                   "s_waitcnt vmcnt(0)"
                   : "=&v"(e) : "v"(pp) : "memory");
      if (e[1] >= tf && e[3] >= tf) break;
    }

    // ---- stage 2 h values to LDS (8B, padded layout) ----
    {
      f32x2 s2; s2[0] = e[0]; s2[1] = e[2];
      *(f32x2*)&hs[tid * 2 + (tid >> 4) * 4] = s2;
    }
    __syncthreads();

    // ---- read own 32-col chunk (broadcast across the 4 gate groups) ----
    const float* rb = &hs[c * 36];
    f32x4 h0 = *(const f32x4*)(rb + 0);
    f32x4 h1 = *(const f32x4*)(rb + 4);
    f32x4 h2v = *(const f32x4*)(rb + 8);
    f32x4 h3 = *(const f32x4*)(rb + 12);
    f32x4 h4 = *(const f32x4*)(rb + 16);
    f32x4 h5 = *(const f32x4*)(rb + 20);
    f32x4 h6 = *(const f32x4*)(rb + 24);
    f32x4 h7 = *(const f32x4*)(rb + 28);

    // ---- 32 vector FMAs ----
    f32x4 va = w0 * h0;
    va += w1 * h1;  va += w2 * h2v; va += w3 * h3;
    va += w4 * h4;  va += w5 * h5;  va += w6 * h6;  va += w7 * h7;
    float a = va[0] + va[1] + va[2] + va[3];

    // ---- reduce over 16 chunks, add gx, gather gates to lane 0 ----
    a += __shfl_xor(a, 1, 64);
    a += __shfl_xor(a, 2, 64);
    a += __shfl_xor(a, 4, 64);
    a += __shfl_xor(a, 8, 64);
    a += gxv;                              // only c==0 lanes carry nonzero gxv
    const float ov = __shfl_xor(a, 16, 64);   // lane0 <- gate o (lane 16)
    const float uv = __shfl_xor(a, 32, 64);   // lane0 <- gate u (lane 32)
    const float fv = __shfl_xor(ov, 32, 64);  // lane0 <- gate f (lane 48)

    // ---- hB at the last step: pure-gx cell from zero state ----
    if (t == SEQLEN - 1) {
      const float go = __shfl_xor(gxv, 16, 64);
      const float gu = __shfl_xor(gxv, 32, 64);
      if (owner) {
        const float cB = sigf(gxv) * tanhfast(gu);
        hB[sq * 512 + j] = sigf(go) * tanhfast(cB);
      }
    }

    // ---- owner: cell update + coherent 8B publish {h, tag} ----
    if (owner) {
      cst = sigf(a) * tanhfast(uv) + sigf(fv) * cst;
      const float h2 = sigf(ov) * tanhfast(cst);
      f32x2 st; st[0] = h2; st[1] = (float)(t + 1);
      float* dp = hbase + (size_t)((((t + 1) & 1) * 1024) + j * 2);
      asm volatile("global_store_dwordx2 %0, %1, off sc0 sc1" :: "v"(dp), "v"(st) : "memory");
    }
  }
}

// ---------------- K3a: s = sigmoid(Wh @ vec + bh), 16 WGs x 16 rows ----------------
__global__ __launch_bounds__(256) void head1(
    const float* __restrict__ hbuf, const float* __restrict__ hB,
    const float* __restrict__ Wh, const float* __restrict__ bh,
    float* __restrict__ sv)
{
  __shared__ __align__(16) float vec[2048];
  const int tid = threadIdx.x;
  const int wg = blockIdx.x;  // 0..15
  // final h (tag 1024) at parity 0: L at hbuf[k*2], R at hbuf[2048 + k*2]
  for (int k = tid; k < 1024; k += 256) {
    float lv, rv;
    if (k < 512) { lv = hbuf[(size_t)k * 2]; rv = hbuf[2048 + (size_t)k * 2]; }
    else         { lv = hB[k - 512];         rv = hB[512 + (k - 512)]; }
    vec[k] = lv * rv;
    vec[1024 + k] = fabsf(lv - rv);
  }
  __syncthreads();
  const int row = wg * 16 + (tid >> 4);
  const int ln = tid & 15;
  const float* wr = Wh + (size_t)row * 2048 + ln * 128;
  const float* vp = vec + ln * 128;
  float acc = 0.0f;
  #pragma unroll
  for (int k = 0; k < 128; k += 4) {
    float4 wv = *(const float4*)(wr + k);
    float4 vv = *(const float4*)(vp + k);
    acc += wv.x*vv.x + wv.y*vv.y + wv.z*vv.z + wv.w*vv.w;
  }
  #pragma unroll
  for (int msk = 1; msk < 16; msk <<= 1) acc += __shfl_xor(acc, msk, 64);
  if (ln == 0) sv[row] = 1.0f / (1.0f + expf(-(acc + bh[row])));
}

// ---------------- K3b: logits = Wp @ s + bp ; log_softmax ----------------
__global__ __launch_bounds__(256) void head2(
    const float* __restrict__ sv, const float* __restrict__ Wp,
    const float* __restrict__ bp, float* __restrict__ out)
{
  __shared__ float s_l[256];
  __shared__ float lg[5];
  const int tid = threadIdx.x;
  s_l[tid] = sv[tid];
  __syncthreads();
  if (tid < 5) {
    float acc = bp[tid];
    for (int k = 0; k < 256; ++k) acc += Wp[tid*256 + k] * s_l[k];
    lg[tid] = acc;
  }
  __syncthreads();
  if (tid == 0) {
    float mx = lg[0];
    #pragma unroll
    for (int i = 1; i < 5; ++i) mx = fmaxf(mx, lg[i]);
    float sum = 0.0f;
    #pragma unroll
    for (int i = 0; i < 5; ++i) sum += expf(lg[i] - mx);
    const float lse = mx + logf(sum);
    #pragma unroll
    for (int i = 0; i < 5; ++i) out[i] = lg[i] - lse;
  }
}

extern "C" void kernel_launch(void* const* d_in, const int* in_sizes, int n_in,
                              void* d_out, int out_size, void* d_ws, size_t ws_size,
                              hipStream_t stream) {
  const int*   l_ids = (const int*)d_in[0];
  const int*   r_ids = (const int*)d_in[1];
  const float* emb   = (const float*)d_in[2];
  const float* Wioux = (const float*)d_in[3];
  const float* bioux = (const float*)d_in[4];
  const float* Wiouh = (const float*)d_in[5];
  const float* biouh = (const float*)d_in[6];
  const float* Wfx   = (const float*)d_in[7];
  const float* bfx   = (const float*)d_in[8];
  const float* Wfh   = (const float*)d_in[9];
  const float* bfh   = (const float*)d_in[10];
  const float* Wh    = (const float*)d_in[11];
  const float* bh    = (const float*)d_in[12];
  const float* Wp    = (const float*)d_in[13];
  const float* bp    = (const float*)d_in[14];
  float* out = (float*)d_out;

  // workspace layout (floats): Gx [2*1024*2048], hbuf [2 seq][2 par][512][2], hB [1024], sv [256]
  float* gx   = (float*)d_ws;
  float* hbuf = gx + (size_t)2*1024*2048;
  float* hB   = hbuf + 4096;
  float* sv   = hB + 1024;

  // zero {h,tag} buffer + hB + sv each launch (graph-captured memset node)
  hipMemsetAsync(hbuf, 0, (4096 + 1024 + 256) * sizeof(float), stream);

  gx_gemm<<<dim3(1024), dim3(256), 0, stream>>>(l_ids, r_ids, emb, Wioux, Wfx,
                                                bioux, biouh, bfx, bfh, gx);
  lstm_scan<<<dim3(256), dim3(256), 0, stream>>>(Wiouh, Wfh, gx, hbuf, hB);
  head1<<<dim3(16), dim3(256), 0, stream>>>(hbuf, hB, Wh, bh, sv);
  head2<<<dim3(1), dim3(256), 0, stream>>>(sv, Wp, bp, out);
  (void)in_sizes; (void)n_in; (void)out_size; (void)ws_size;
}

// Round 7
// 2166.964 us; speedup vs baseline: 1.3063x; 1.3063x over previous
//
#include <hip/hip_runtime.h>
#include <math.h>

#define SEQLEN 1024
#define DIM 512
#define MM 512

typedef float f32x4 __attribute__((ext_vector_type(4)));
typedef float f32x2 __attribute__((ext_vector_type(2)));

__device__ __forceinline__ float sigf(float x) {
  return __builtin_amdgcn_rcpf(1.0f + __expf(-x));
}
__device__ __forceinline__ float tanhfast(float x) {
  return 1.0f - 2.0f * __builtin_amdgcn_rcpf(1.0f + __expf(2.0f * x));
}

// ---------------- K1: Gx[seq][t][g] = emb[ids[t]] . Wxcat[g] + bias_cat[g] ----------------
__global__ __launch_bounds__(256) void gx_gemm(
    const int* __restrict__ l_ids, const int* __restrict__ r_ids,
    const float* __restrict__ emb,
    const float* __restrict__ Wioux, const float* __restrict__ Wfx,
    const float* __restrict__ bioux, const float* __restrict__ biouh,
    const float* __restrict__ bfx, const float* __restrict__ bfh,
    float* __restrict__ gx)
{
  __shared__ __align__(16) float At[32][68];
  __shared__ __align__(16) float Bt[32][68];
  const int tid = threadIdx.x;
  const int bid = blockIdx.x;
  const int seq = bid >> 9;
  const int tt  = (bid >> 5) & 15;
  const int gt  = bid & 31;
  const int t0 = tt * 64, g0 = gt * 64;
  const int* ids = seq ? r_ids : l_ids;

  const int li = tid >> 2;
  const int lk = (tid & 3) * 8;
  const float* arow = emb + (size_t)ids[t0 + li] * DIM;
  const int gg = g0 + li;
  const float* brow = (gg < 1536) ? (Wioux + (size_t)gg * DIM)
                                  : (Wfx + (size_t)(gg - 1536) * DIM);
  const int tr = tid >> 4;
  const int tc = tid & 15;

  float acc[4][4];
  #pragma unroll
  for (int i = 0; i < 4; ++i) { acc[i][0]=0.f; acc[i][1]=0.f; acc[i][2]=0.f; acc[i][3]=0.f; }

  for (int kb = 0; kb < 16; ++kb) {
    const int k0 = kb * 32;
    float4 av0 = *(const float4*)(arow + k0 + lk);
    float4 av1 = *(const float4*)(arow + k0 + lk + 4);
    float4 bv0 = *(const float4*)(brow + k0 + lk);
    float4 bv1 = *(const float4*)(brow + k0 + lk + 4);
    __syncthreads();
    At[lk+0][li]=av0.x; At[lk+1][li]=av0.y; At[lk+2][li]=av0.z; At[lk+3][li]=av0.w;
    At[lk+4][li]=av1.x; At[lk+5][li]=av1.y; At[lk+6][li]=av1.z; At[lk+7][li]=av1.w;
    Bt[lk+0][li]=bv0.x; Bt[lk+1][li]=bv0.y; Bt[lk+2][li]=bv0.z; Bt[lk+3][li]=bv0.w;
    Bt[lk+4][li]=bv1.x; Bt[lk+5][li]=bv1.y; Bt[lk+6][li]=bv1.z; Bt[lk+7][li]=bv1.w;
    __syncthreads();
    #pragma unroll
    for (int k = 0; k < 32; ++k) {
      float4 a4 = *(const float4*)&At[k][tr*4];
      float4 b4 = *(const float4*)&Bt[k][tc*4];
      acc[0][0]+=a4.x*b4.x; acc[0][1]+=a4.x*b4.y; acc[0][2]+=a4.x*b4.z; acc[0][3]+=a4.x*b4.w;
      acc[1][0]+=a4.y*b4.x; acc[1][1]+=a4.y*b4.y; acc[1][2]+=a4.y*b4.z; acc[1][3]+=a4.y*b4.w;
      acc[2][0]+=a4.z*b4.x; acc[2][1]+=a4.z*b4.y; acc[2][2]+=a4.z*b4.z; acc[2][3]+=a4.z*b4.w;
      acc[3][0]+=a4.w*b4.x; acc[3][1]+=a4.w*b4.y; acc[3][2]+=a4.w*b4.z; acc[3][3]+=a4.w*b4.w;
    }
  }
  const int gc = g0 + tc * 4;
  float badd[4];
  #pragma unroll
  for (int jj = 0; jj < 4; ++jj) {
    int g = gc + jj;
    badd[jj] = (g < 1536) ? (bioux[g] + biouh[g]) : (bfx[g-1536] + bfh[g-1536]);
  }
  #pragma unroll
  for (int ii = 0; ii < 4; ++ii) {
    float4 r;
    r.x = acc[ii][0] + badd[0];
    r.y = acc[ii][1] + badd[1];
    r.z = acc[ii][2] + badd[2];
    r.w = acc[ii][3] + badd[3];
    size_t off = ((size_t)seq * SEQLEN + (size_t)(t0 + tr*4 + ii)) * 2048 + gc;
    *(float4*)(gx + off) = r;
  }
}

// ---------------- K2: persistent scan, 32 WGs x 512 thr, 2-deep pipelined poll ------------
// hbuf: [2 parity][512 j][4] = {h_l, tag, h_r, tag}; 16B atomic coherent stores.
// Thread (jl=tid>>5, g=(tid>>4)&1, b=tid&15): gate-rows {2g,2g+1} of j=wg*16+jl,
// cols [b*32,b*32+32) -> 16 NAMED f32x4 weight regs (64 floats). Each thread polls ONE
// global entry j_p = tid with TWO loads always in flight (vmcnt(1) ping-pong) -> poll
// period ~100cyc instead of ~1100 (serial latency-bound).
__global__ __launch_bounds__(512, 1) void lstm_scan(
    const float* __restrict__ Wiouh, const float* __restrict__ Wfh,
    const float* __restrict__ gx,
    float* __restrict__ hbuf,       // zeroed by memset (tags start at 0)
    float* __restrict__ hB)         // [2 seq][512]
{
  const int tid = threadIdx.x;
  const int wg  = blockIdx.x;       // 0..31
  const int b   = tid & 15;
  const int g   = (tid >> 4) & 1;
  const int jl  = tid >> 5;         // 0..15
  const int j   = wg * 16 + jl;
  const bool owner = ((tid & 31) == 0);

  // weights: rows {2g, 2g+1} of j (gate order i,o,u,f), cols b*32..b*32+31
  const int gA = 2 * g, gB = 2 * g + 1;
  const float* rA = ((gA < 3) ? (Wiouh + ((size_t)(gA * 512 + j)) * MM)
                              : (Wfh + (size_t)j * MM)) + b * 32;
  const float* rB = ((gB < 3) ? (Wiouh + ((size_t)(gB * 512 + j)) * MM)
                              : (Wfh + (size_t)j * MM)) + b * 32;
  f32x4 wa0 = *(const f32x4*)(rA + 0),  wa1 = *(const f32x4*)(rA + 4);
  f32x4 wa2 = *(const f32x4*)(rA + 8),  wa3 = *(const f32x4*)(rA + 12);
  f32x4 wa4 = *(const f32x4*)(rA + 16), wa5 = *(const f32x4*)(rA + 20);
  f32x4 wa6 = *(const f32x4*)(rA + 24), wa7 = *(const f32x4*)(rA + 28);
  f32x4 wb0 = *(const f32x4*)(rB + 0),  wb1 = *(const f32x4*)(rB + 4);
  f32x4 wb2 = *(const f32x4*)(rB + 8),  wb3 = *(const f32x4*)(rB + 12);
  f32x4 wb4 = *(const f32x4*)(rB + 16), wb5 = *(const f32x4*)(rB + 20);
  f32x4 wb6 = *(const f32x4*)(rB + 24), wb7 = *(const f32x4*)(rB + 28);
  asm volatile("" : "+v"(wa0), "+v"(wa1), "+v"(wa2), "+v"(wa3),
                    "+v"(wa4), "+v"(wa5), "+v"(wa6), "+v"(wa7));
  asm volatile("" : "+v"(wb0), "+v"(wb1), "+v"(wb2), "+v"(wb3),
                    "+v"(wb4), "+v"(wb5), "+v"(wb6), "+v"(wb7));

  // h staging, double-buffered by parity: 16 chunks x (64 data + 4 pad) floats
  __shared__ __align__(16) float hs[2][16 * 68];

  float cl = 0.0f, cr = 0.0f;       // persistent c (owner lanes)
  const float* gxs = gx;

  for (int t = 0; t < SEQLEN; ++t) {
    // ---- 2-deep pipelined poll of entry j_p = tid ----
    const float* pp = hbuf + (size_t)((t & 1) * 512 + tid) * 4;
    const float tf = (float)t;
    f32x4 eA, eB, e;
    asm volatile("global_load_dwordx4 %0, %2, off sc0 sc1\n\t"
                 "global_load_dwordx4 %1, %2, off sc0 sc1"
                 : "=&v"(eA), "=&v"(eB) : "v"(pp) : "memory");
    for (;;) {
      asm volatile("s_waitcnt vmcnt(1)" ::: "memory");
      __builtin_amdgcn_sched_barrier(0);
      if (eA[1] >= tf && eA[3] >= tf) { e = eA; break; }
      asm volatile("global_load_dwordx4 %0, %1, off sc0 sc1" : "=&v"(eA) : "v"(pp) : "memory");
      asm volatile("s_waitcnt vmcnt(1)" ::: "memory");
      __builtin_amdgcn_sched_barrier(0);
      if (eB[1] >= tf && eB[3] >= tf) { e = eB; break; }
      asm volatile("global_load_dwordx4 %0, %1, off sc0 sc1" : "=&v"(eB) : "v"(pp) : "memory");
    }
    asm volatile("s_waitcnt vmcnt(0)" ::: "memory");
    __builtin_amdgcn_sched_barrier(0);

    // ---- gx pre-acts for the owner (latency hidden under stage+FMA) ----
    float gl0=0.f, gl1=0.f, gl2=0.f, gl3=0.f, gr0=0.f, gr1=0.f, gr2=0.f, gr3=0.f;
    if (owner) {
      const float* gpl = gxs + (size_t)t * 2048 + j;
      const float* gpr = gxs + ((size_t)SEQLEN + t) * 2048 + j;
      gl0 = gpl[0]; gl1 = gpl[512]; gl2 = gpl[1024]; gl3 = gpl[1536];
      gr0 = gpr[0]; gr1 = gpr[512]; gr2 = gpr[1024]; gr3 = gpr[1536];
    }

    // ---- stage {hl,hr} pair to LDS (8B), double-buffered parity ----
    {
      f32x2 s2; s2[0] = e[0]; s2[1] = e[2];
      *(f32x2*)&hs[t & 1][(tid >> 5) * 68 + (tid & 31) * 2] = s2;
    }
    __syncthreads();

    // ---- read own 32-col chunk (pairs), broadcast across jl/g groups ----
    const float* rb = &hs[t & 1][b * 68];
    float a0l = 0.f, a0r = 0.f, a1l = 0.f, a1r = 0.f;
    #define STEPQ(q, WA, WB) { \
      f32x4 v0 = *(const f32x4*)(rb + (q)*8); \
      f32x4 v1 = *(const f32x4*)(rb + (q)*8 + 4); \
      a0l += WA[0]*v0[0]; a0r += WA[0]*v0[1]; \
      a1l += WB[0]*v0[0]; a1r += WB[0]*v0[1]; \
      a0l += WA[1]*v0[2]; a0r += WA[1]*v0[3]; \
      a1l += WB[1]*v0[2]; a1r += WB[1]*v0[3]; \
      a0l += WA[2]*v1[0]; a0r += WA[2]*v1[1]; \
      a1l += WB[2]*v1[0]; a1r += WB[2]*v1[1]; \
      a0l += WA[3]*v1[2]; a0r += WA[3]*v1[3]; \
      a1l += WB[3]*v1[2]; a1r += WB[3]*v1[3]; \
    }
    STEPQ(0, wa0, wb0) STEPQ(1, wa1, wb1) STEPQ(2, wa2, wb2) STEPQ(3, wa3, wb3)
    STEPQ(4, wa4, wb4) STEPQ(5, wa5, wb5) STEPQ(6, wa6, wb6) STEPQ(7, wa7, wb7)
    #undef STEPQ

    // ---- reduce over b (16 lanes) ----
    #pragma unroll
    for (int m = 1; m < 16; m <<= 1) {
      a0l += __shfl_xor(a0l, m, 64);
      a1l += __shfl_xor(a1l, m, 64);
      a0r += __shfl_xor(a0r, m, 64);
      a1r += __shfl_xor(a1r, m, 64);
    }
    // cross-g merge: g=0 lanes (rows i,o) fetch u,f sums from g=1 partner
    const float p0l = __shfl_xor(a0l, 16, 64);
    const float p1l = __shfl_xor(a1l, 16, 64);
    const float p0r = __shfl_xor(a0r, 16, 64);
    const float p1r = __shfl_xor(a1r, 16, 64);

    // ---- owner: cell update + coherent 16B publish {h_l, tag, h_r, tag} ----
    if (owner) {
      const float il = a0l + gl0, ol = a1l + gl1, ul = p0l + gl2, fl = p1l + gl3;
      const float ir = a0r + gr0, orr = a1r + gr1, ur = p0r + gr2, fr = p1r + gr3;
      cl = sigf(il) * tanhfast(ul) + sigf(fl) * cl;
      cr = sigf(ir) * tanhfast(ur) + sigf(fr) * cr;
      const float h2l = sigf(ol) * tanhfast(cl);
      const float h2r = sigf(orr) * tanhfast(cr);
      const float tg = (float)(t + 1);
      f32x4 st; st[0] = h2l; st[1] = tg; st[2] = h2r; st[3] = tg;
      float* dp = hbuf + (size_t)((((t + 1) & 1) * 512 + j)) * 4;
      asm volatile("global_store_dwordx4 %0, %1, off sc0 sc1" :: "v"(dp), "v"(st) : "memory");
      if (t == SEQLEN - 1) {
        // hB = cell(x_last, 0, 0).h ; gate pre-acts are exactly the gx values
        const float cBl = sigf(gl0) * tanhfast(gl2);
        const float cBr = sigf(gr0) * tanhfast(gr2);
        hB[j]       = sigf(gl1) * tanhfast(cBl);
        hB[512 + j] = sigf(gr1) * tanhfast(cBr);
      }
    }
  }
}

// ---------------- K3a: s = sigmoid(Wh @ vec + bh), 16 WGs x 16 rows ----------------
__global__ __launch_bounds__(256) void head1(
    const float* __restrict__ hbuf, const float* __restrict__ hB,
    const float* __restrict__ Wh, const float* __restrict__ bh,
    float* __restrict__ sv)
{
  __shared__ __align__(16) float vec[2048];
  const int tid = threadIdx.x;
  const int wg = blockIdx.x;  // 0..15
  // final h (tag 1024) lives at parity 0: entry j -> {h_l at j*4, h_r at j*4+2}
  for (int k = tid; k < 1024; k += 256) {
    float lv, rv;
    if (k < 512) { lv = hbuf[(size_t)k * 4]; rv = hbuf[(size_t)k * 4 + 2]; }
    else         { lv = hB[k - 512];         rv = hB[512 + (k - 512)]; }
    vec[k] = lv * rv;
    vec[1024 + k] = fabsf(lv - rv);
  }
  __syncthreads();
  const int row = wg * 16 + (tid >> 4);
  const int ln = tid & 15;
  const float* wr = Wh + (size_t)row * 2048 + ln * 128;
  const float* vp = vec + ln * 128;
  float acc = 0.0f;
  #pragma unroll
  for (int k = 0; k < 128; k += 4) {
    float4 wv = *(const float4*)(wr + k);
    float4 vv = *(const float4*)(vp + k);
    acc += wv.x*vv.x + wv.y*vv.y + wv.z*vv.z + wv.w*vv.w;
  }
  #pragma unroll
  for (int msk = 1; msk < 16; msk <<= 1) acc += __shfl_xor(acc, msk, 64);
  if (ln == 0) sv[row] = 1.0f / (1.0f + expf(-(acc + bh[row])));
}

// ---------------- K3b: logits = Wp @ s + bp ; log_softmax ----------------
__global__ __launch_bounds__(256) void head2(
    const float* __restrict__ sv, const float* __restrict__ Wp,
    const float* __restrict__ bp, float* __restrict__ out)
{
  __shared__ float s_l[256];
  __shared__ float lg[5];
  const int tid = threadIdx.x;
  s_l[tid] = sv[tid];
  __syncthreads();
  if (tid < 5) {
    float acc = bp[tid];
    for (int k = 0; k < 256; ++k) acc += Wp[tid*256 + k] * s_l[k];
    lg[tid] = acc;
  }
  __syncthreads();
  if (tid == 0) {
    float mx = lg[0];
    #pragma unroll
    for (int i = 1; i < 5; ++i) mx = fmaxf(mx, lg[i]);
    float sum = 0.0f;
    #pragma unroll
    for (int i = 0; i < 5; ++i) sum += expf(lg[i] - mx);
    const float lse = mx + logf(sum);
    #pragma unroll
    for (int i = 0; i < 5; ++i) out[i] = lg[i] - lse;
  }
}

extern "C" void kernel_launch(void* const* d_in, const int* in_sizes, int n_in,
                              void* d_out, int out_size, void* d_ws, size_t ws_size,
                              hipStream_t stream) {
  const int*   l_ids = (const int*)d_in[0];
  const int*   r_ids = (const int*)d_in[1];
  const float* emb   = (const float*)d_in[2];
  const float* Wioux = (const float*)d_in[3];
  const float* bioux = (const float*)d_in[4];
  const float* Wiouh = (const float*)d_in[5];
  const float* biouh = (const float*)d_in[6];
  const float* Wfx   = (const float*)d_in[7];
  const float* bfx   = (const float*)d_in[8];
  const float* Wfh   = (const float*)d_in[9];
  const float* bfh   = (const float*)d_in[10];
  const float* Wh    = (const float*)d_in[11];
  const float* bh    = (const float*)d_in[12];
  const float* Wp    = (const float*)d_in[13];
  const float* bp    = (const float*)d_in[14];
  float* out = (float*)d_out;

  // workspace layout (floats): Gx [2*1024*2048], hbuf [2 par][512][4], hB [1024], sv [256]
  float* gx   = (float*)d_ws;
  float* hbuf = gx + (size_t)2*1024*2048;
  float* hB   = hbuf + 4096;
  float* sv   = hB + 1024;

  hipMemsetAsync(hbuf, 0, (4096 + 1024 + 256) * sizeof(float), stream);

  gx_gemm<<<dim3(1024), dim3(256), 0, stream>>>(l_ids, r_ids, emb, Wioux, Wfx,
                                                bioux, biouh, bfx, bfh, gx);
  lstm_scan<<<dim3(32), dim3(512), 0, stream>>>(Wiouh, Wfh, gx, hbuf, hB);
  head1<<<dim3(16), dim3(256), 0, stream>>>(hbuf, hB, Wh, bh, sv);
  head2<<<dim3(1), dim3(256), 0, stream>>>(sv, Wp, bp, out);
  (void)in_sizes; (void)n_in; (void)out_size; (void)ws_size;
}